// Round 1
// baseline (100.988 us; speedup 1.0000x reference)
//
#include <hip/hip_runtime.h>

typedef __attribute__((ext_vector_type(8))) short    short8;
typedef __attribute__((ext_vector_type(4))) float    f32x4;
typedef __attribute__((ext_vector_type(4))) _Float16 half4;

#define SCL2E (0.125f * 1.44269504088896341f)   // scale * log2(e)

__device__ __forceinline__ unsigned short f2bf(float f) {
    union { float f; unsigned u; } v; v.f = f;
    unsigned u = v.u;
    u += 0x7fffu + ((u >> 16) & 1u);            // round-to-nearest-even
    return (unsigned short)(u >> 16);
}

// B=4, L=S=2048, H=8, E=D=64.  Layout [B,L,H,E]: per-(b,h) row stride = H*E = 512 floats.
__global__ __launch_bounds__(128, 2)
void attn_fwd_kernel(const float* __restrict__ Q, const float* __restrict__ K,
                     const float* __restrict__ V, float* __restrict__ O) {
    __shared__ __align__(16) unsigned short lds_q[64 * 64];  // bf16 bits, [q][e], swizzled
    __shared__ __align__(16) unsigned short lds_k[64 * 64];  // bf16 bits, [kv][e], swizzled
    __shared__ __align__(16) unsigned short lds_v[64 * 64];  // f16 bits, TRANSPOSED [d][kv], swizzled

    const int tid  = threadIdx.x;
    const int lane = tid & 63;
    const int wv   = tid >> 6;        // wave 0..1
    const int lq   = lane & 15;
    const int g    = lane >> 4;       // 0..3

    // XCD-aware work mapping: consecutive blockIdx round-robin XCDs (bid%8).
    // Give each XCD the 32 q-tiles of bh == xcd (mod 8) so its 32 CUs stream
    // one (b,h)'s 2MB KV in lockstep -> L2 hits.
    const int bid  = blockIdx.x;
    const int xcd  = bid & 7;
    const int slot = bid >> 3;              // 0..127
    const int qt   = slot & 31;             // q tile 0..31
    const int bh   = ((slot >> 5) << 3) | xcd;
    const int b    = bh >> 3, h = bh & 7;

    const size_t base = ((size_t)b * 2048 * 8 + (size_t)h) * 64;
    const float* Qg = Q + base;
    const float* Kg = K + base;
    const float* Vg = V + base;
    float*       Og = O + base;

    const int q0 = qt * 64;

    // ---- stage Q tile (64 x 64) as bf16 into LDS (swizzled) ----
#pragma unroll
    for (int p = 0; p < 16; ++p) {
        int r = (tid >> 5) + p * 4;              // 0..63
        int e = (tid & 31) * 2;
        const float* src = Qg + (size_t)(q0 + r) * 512 + e;
        float x0 = src[0], x1 = src[1];
        unsigned pk = (unsigned)f2bf(x0) | ((unsigned)f2bf(x1) << 16);
        *(unsigned*)&lds_q[(r * 64 + e) ^ ((r & 7) << 3)] = pk;
    }
    __syncthreads();

    // Q fragments (B-operand of 16x16x32: col q = lane&15, e = 8*g + j)
    short8 qf[2][2];
#pragma unroll
    for (int qc = 0; qc < 2; ++qc) {
        int row = wv * 32 + qc * 16 + lq;
#pragma unroll
        for (int j = 0; j < 2; ++j)
            qf[qc][j] = *(const short8*)&lds_q[(row * 64 + j * 32 + g * 8) ^ ((row & 7) << 3)];
    }

    f32x4 acc[2][4];
#pragma unroll
    for (int qc = 0; qc < 2; ++qc)
#pragma unroll
        for (int dc = 0; dc < 4; ++dc)
            acc[qc][dc] = (f32x4){0.f, 0.f, 0.f, 0.f};
    float mrow[2] = {-1e30f, -1e30f};
    float lrow[2] = {0.f, 0.f};

    for (int t = 0; t < 32; ++t) {
        const int kv0 = t * 64;
        __syncthreads();   // previous tile's reads done before overwrite

        // ---- stage K tile (64 kv x 64 e) as bf16 ----
#pragma unroll
        for (int p = 0; p < 16; ++p) {
            int r = (tid >> 5) + p * 4;
            int e = (tid & 31) * 2;
            const float* src = Kg + (size_t)(kv0 + r) * 512 + e;
            float x0 = src[0], x1 = src[1];
            unsigned pk = (unsigned)f2bf(x0) | ((unsigned)f2bf(x1) << 16);
            *(unsigned*)&lds_k[(r * 64 + e) ^ ((r & 7) << 3)] = pk;
        }
        // ---- stage V tile TRANSPOSED [d][kv] as f16 ----
#pragma unroll
        for (int p = 0; p < 16; ++p) {
            int d  = tid & 63;
            int kv = (p * 2 + (tid >> 6)) * 2;   // even 0..62
            float v0 = Vg[(size_t)(kv0 + kv) * 512 + d];
            float v1 = Vg[(size_t)(kv0 + kv + 1) * 512 + d];
            union { _Float16 hh[2]; unsigned u; } pk;
            pk.hh[0] = (_Float16)v0; pk.hh[1] = (_Float16)v1;
            *(unsigned*)&lds_v[(d * 64 + kv) ^ ((d & 15) << 2)] = pk.u;
        }
        __syncthreads();

        // ---- S^T = K · Q^T  (D: col=q=lane&15, row=kv_local=4g+reg) ----
        f32x4 sfr[2][4];
#pragma unroll
        for (int kc = 0; kc < 4; ++kc) {
            int row = kc * 16 + lq;
            short8 kf0 = *(const short8*)&lds_k[(row * 64 + 0  + g * 8) ^ ((row & 7) << 3)];
            short8 kf1 = *(const short8*)&lds_k[(row * 64 + 32 + g * 8) ^ ((row & 7) << 3)];
#pragma unroll
            for (int qc = 0; qc < 2; ++qc) {
                f32x4 s = __builtin_amdgcn_mfma_f32_16x16x32_bf16(
                    kf0, qf[qc][0], (f32x4){0.f, 0.f, 0.f, 0.f}, 0, 0, 0);
                s = __builtin_amdgcn_mfma_f32_16x16x32_bf16(kf1, qf[qc][1], s, 0, 0, 0);
                sfr[qc][kc] = s;
            }
        }

        // ---- online softmax (per q-col; lane holds 16 kv of its q) ----
        half4 pf[2][4];
#pragma unroll
        for (int qc = 0; qc < 2; ++qc) {
            float smax = -1e30f;
#pragma unroll
            for (int kc = 0; kc < 4; ++kc)
#pragma unroll
                for (int r = 0; r < 4; ++r) smax = fmaxf(smax, sfr[qc][kc][r]);
            smax = fmaxf(smax, __shfl_xor(smax, 16));
            smax = fmaxf(smax, __shfl_xor(smax, 32));
            float mn    = fmaxf(mrow[qc], smax);
            float alpha = __builtin_amdgcn_exp2f((mrow[qc] - mn) * SCL2E);
            mrow[qc]    = mn;
            float msc   = mn * SCL2E;
            float psum  = 0.f;
#pragma unroll
            for (int kc = 0; kc < 4; ++kc)
#pragma unroll
                for (int r = 0; r < 4; ++r) {
                    float p = __builtin_amdgcn_exp2f(sfr[qc][kc][r] * SCL2E - msc);
                    psum += p;
                    pf[qc][kc][r] = (_Float16)p;
                }
            psum += __shfl_xor(psum, 16);
            psum += __shfl_xor(psum, 32);
            lrow[qc] = lrow[qc] * alpha + psum;
#pragma unroll
            for (int dc = 0; dc < 4; ++dc) acc[qc][dc] *= alpha;
        }

        // ---- O^T += V^T · P^T  (A: row=d=lane&15, kv=4g+j; B = P^T direct) ----
#pragma unroll
        for (int dc = 0; dc < 4; ++dc) {
            int dd = dc * 16 + lq;
#pragma unroll
            for (int kc = 0; kc < 4; ++kc) {
                half4 vf = *(const half4*)&lds_v[(dd * 64 + kc * 16 + g * 4) ^ ((dd & 15) << 2)];
                acc[0][dc] = __builtin_amdgcn_mfma_f32_16x16x16f16(vf, pf[0][kc], acc[0][dc], 0, 0, 0);
                acc[1][dc] = __builtin_amdgcn_mfma_f32_16x16x16f16(vf, pf[1][kc], acc[1][dc], 0, 0, 0);
            }
        }
    }

    // ---- epilogue: O[q][d] = acc^T / l  (D: row=d_local=4g+reg, col=q) ----
#pragma unroll
    for (int qc = 0; qc < 2; ++qc) {
        float inv = 1.f / lrow[qc];
        int qrow  = q0 + wv * 32 + qc * 16 + lq;
#pragma unroll
        for (int dc = 0; dc < 4; ++dc) {
            f32x4 o = acc[qc][dc] * inv;
            *(f32x4*)(Og + (size_t)qrow * 512 + dc * 16 + g * 4) = o;
        }
    }
}

extern "C" void kernel_launch(void* const* d_in, const int* in_sizes, int n_in,
                              void* d_out, int out_size, void* d_ws, size_t ws_size,
                              hipStream_t stream) {
    const float* Q = (const float*)d_in[0];
    const float* K = (const float*)d_in[1];
    const float* V = (const float*)d_in[2];
    float* O = (float*)d_out;
    // grid: 32 bh * 32 q-tiles = 1024 blocks, 128 threads
    attn_fwd_kernel<<<dim3(1024), dim3(128), 0, stream>>>(Q, K, V, O);
}

// Round 3
// 75.288 us; speedup vs baseline: 1.3414x; 1.3414x over previous
//
#include <hip/hip_runtime.h>

typedef __attribute__((ext_vector_type(4)))  float    f32x4;
typedef __attribute__((ext_vector_type(16))) float    f32x16;
typedef __attribute__((ext_vector_type(8)))  _Float16 half8;
typedef __attribute__((ext_vector_type(2)))  __fp16   fp16x2;
typedef __attribute__((ext_vector_type(4)))  _Float16 half4;
typedef __attribute__((ext_vector_type(8)))  short    short8;

#define SCL2E 0.18033688011112042f   // (1/8) * log2(e)

__device__ __forceinline__ unsigned short f2h_bits(float x) {
    union { _Float16 h; unsigned short u; } c;
    c.h = (_Float16)x;
    return c.u;
}

__device__ __forceinline__ void gl_lds16(const unsigned short* g, unsigned short* l) {
    __builtin_amdgcn_global_load_lds((const __attribute__((address_space(1))) void*)g,
                                     (__attribute__((address_space(3))) void*)l, 16, 0, 0);
}

// ---------------- prepass: Q/K rows -> f16, perm(bit2<->bit3 of e) + swizzle ----------------
// in:  src[b][row][h][e] f32   out: dst[bh][row][perm_swz(e)] f16-bits
__global__ __launch_bounds__(256)
void cvt_rows_kernel(const float* __restrict__ src, unsigned short* __restrict__ dst) {
    int t   = blockIdx.x * 256 + threadIdx.x;     // 1,048,576 threads
    int eg  = t & 15;                             // 4-element group within row
    int gr  = t >> 4;                             // bh*2048 + row
    int row = gr & 2047, bh = gr >> 11;
    int b = bh >> 3, h = bh & 7;
    const float* sp = src + (((size_t)b * 2048 + row) * 8 + h) * 64 + eg * 4;
    f32x4 v = *(const f32x4*)sp;
    int cg = (eg & ~3) | ((eg & 1) << 1) | ((eg >> 1) & 1);   // swap bits 0,1 (== e bits 2,3)
    cg ^= (row & 7) << 1;                                     // bank swizzle (el bits 3..5)
    union { unsigned short s[4]; unsigned long long u; } o;
    o.s[0] = f2h_bits(v[0]); o.s[1] = f2h_bits(v[1]);
    o.s[2] = f2h_bits(v[2]); o.s[3] = f2h_bits(v[3]);
    *(unsigned long long*)(dst + (size_t)gr * 64 + cg * 4) = o.u;
}

// ---------------- prepass: V -> f16 transposed [bh][d][kv], perm+swizzle on kv ----------------
__global__ __launch_bounds__(256)
void cvt_vT_kernel(const float* __restrict__ src, unsigned short* __restrict__ dst) {
    int t   = blockIdx.x * 256 + threadIdx.x;     // 1,048,576 threads
    int d   = t & 63;
    int g   = t >> 6;                             // bh*512 + kv4
    int kv4 = g & 511, bh = g >> 9;
    int b = bh >> 3, h = bh & 7;
    int kv = kv4 * 4;
    const float* sp = src + (((size_t)b * 2048 + kv) * 8 + h) * 64 + d;
    float v0 = sp[0], v1 = sp[512], v2 = sp[1024], v3 = sp[1536];  // coalesced per row
    int lg  = kv4 & 15;                                            // group within 64-kv tile
    int lgp = (lg & ~3) | ((lg & 1) << 1) | ((lg >> 1) & 1);
    lgp ^= (d & 7) << 1;
    union { unsigned short s[4]; unsigned long long u; } o;
    o.s[0] = f2h_bits(v0); o.s[1] = f2h_bits(v1);
    o.s[2] = f2h_bits(v2); o.s[3] = f2h_bits(v3);
    *(unsigned long long*)(dst + ((size_t)bh * 64 + d) * 2048 + (kv4 & ~15) * 4 + lgp * 4) = o.u;
}

// ---------------- main: 32x32 swapped-QK^T flash attention ----------------
// 4 waves, QBLK=128 (32 q/wave), KVB=64 double-buffered.
__global__ __launch_bounds__(256, 2)
void attn_v2_kernel(const unsigned short* __restrict__ wsQ,
                    const unsigned short* __restrict__ wsK,
                    const unsigned short* __restrict__ wsV,
                    float* __restrict__ O) {
    __shared__ __align__(16) unsigned short lds_q[128 * 64];
    __shared__ __align__(16) unsigned short lds_k[2][64 * 64];
    __shared__ __align__(16) unsigned short lds_v[2][64 * 64];   // V^T [d][kv]

    const int tid  = threadIdx.x;
    const int lane = tid & 63;
    const int wq   = tid >> 6;          // wave -> q chunk
    const int lq   = lane & 31;
    const int hi   = lane >> 5;
    const int swz  = (lq & 7) << 3;

    const int bid = blockIdx.x;
    const int xcd = bid & 7, slot = bid >> 3;
    const int qt  = slot & 15;
    const int bh  = ((slot >> 4) << 3) | xcd;   // XCD-local bh
    const int q0  = qt * 128;

    const unsigned short* Qsrc = wsQ + ((size_t)bh * 2048 + q0) * 64;
    const unsigned short* Ksrc = wsK + (size_t)bh * 2048 * 64;
    const unsigned short* Vsrc = wsV + (size_t)bh * 64 * 2048;
    float* Og = O + ((size_t)(bh >> 3) * 2048 * 8 + (bh & 7)) * 64;

    // stage Q (16KB) + tile 0 (K,V 8KB each) via global_load_lds DMA
#pragma unroll
    for (int p = 0; p < 4; ++p) {
        int s = tid + 256 * p;
        gl_lds16(Qsrc + s * 8, &lds_q[s * 8]);
    }
#pragma unroll
    for (int p = 0; p < 2; ++p) {
        int s = tid + 256 * p;
        gl_lds16(Ksrc + s * 8, &lds_k[0][s * 8]);
        int d = s >> 3, kvl = (s & 7) * 8;
        gl_lds16(Vsrc + (size_t)d * 2048 + kvl, &lds_v[0][s * 8]);
    }
    __syncthreads();

    int off[4];
#pragma unroll
    for (int ks = 0; ks < 4; ++ks) off[ks] = (ks * 16 + hi * 8) ^ swz;

    half8 qf[4];
    {
        int qrow = wq * 32 + lq;
#pragma unroll
        for (int ks = 0; ks < 4; ++ks)
            qf[ks] = *(const half8*)&lds_q[qrow * 64 + off[ks]];
    }

    f32x16 acc0 = {0.f,0.f,0.f,0.f,0.f,0.f,0.f,0.f,0.f,0.f,0.f,0.f,0.f,0.f,0.f,0.f};
    f32x16 acc1 = acc0;
    float mrow = -1e30f, lrow = 0.f;

    for (int t = 0; t < 32; ++t) {
        const int cur = t & 1;
        if (t + 1 < 32) {   // stage next tile into other buffer
            const int nxt = cur ^ 1;
            const size_t kv0 = (size_t)(t + 1) * 64;
            const unsigned short* kt = Ksrc + kv0 * 64;
#pragma unroll
            for (int p = 0; p < 2; ++p) {
                int s = tid + 256 * p;
                gl_lds16(kt + s * 8, &lds_k[nxt][s * 8]);
                int d = s >> 3, kvl = (s & 7) * 8;
                gl_lds16(Vsrc + (size_t)d * 2048 + kv0 + kvl, &lds_v[nxt][s * 8]);
            }
        }

        // ---- S^T = K · Q^T : D col=q=lq, row=kv_local=(r&3)+8(r>>2)+4hi ----
        const unsigned short* kb = lds_k[cur];
        f32x16 s0 = {0.f,0.f,0.f,0.f,0.f,0.f,0.f,0.f,0.f,0.f,0.f,0.f,0.f,0.f,0.f,0.f};
        f32x16 s1 = s0;
#pragma unroll
        for (int ks = 0; ks < 4; ++ks) {
            half8 kf0 = *(const half8*)&kb[lq * 64 + off[ks]];
            half8 kf1 = *(const half8*)&kb[(32 + lq) * 64 + off[ks]];
            s0 = __builtin_amdgcn_mfma_f32_32x32x16_f16(kf0, qf[ks], s0, 0, 0, 0);
            s1 = __builtin_amdgcn_mfma_f32_32x32x16_f16(kf1, qf[ks], s1, 0, 0, 0);
        }

        // ---- online softmax (all state at q = lane&31; hi halves combined by shfl 32) ----
        float smax = s0[0];
#pragma unroll
        for (int r = 1; r < 16; ++r) smax = fmaxf(smax, s0[r]);
#pragma unroll
        for (int r = 0; r < 16; ++r) smax = fmaxf(smax, s1[r]);
        smax = fmaxf(smax, __shfl_xor(smax, 32));

        if (!__all(smax - mrow <= 22.0f)) {       // defer-max: p bounded by 2^4
            float mnew  = fmaxf(mrow, smax);
            float alpha = __builtin_amdgcn_exp2f((mrow - mnew) * SCL2E);
            mrow = mnew;
            lrow *= alpha;
            acc0 *= alpha;
            acc1 *= alpha;
        }
        const float msc = mrow * SCL2E;
        float p0[16], p1[16];
        float psum = 0.f;
#pragma unroll
        for (int r = 0; r < 16; ++r) {
            p0[r] = __builtin_amdgcn_exp2f(s0[r] * SCL2E - msc);
            p1[r] = __builtin_amdgcn_exp2f(s1[r] * SCL2E - msc);
            psum += p0[r] + p1[r];
        }
        psum += __shfl_xor(psum, 32);
        lrow += psum;

        // ---- P -> f16 B-operand frags (register-direct, kc = kv 16-chunk) ----
        half8 pf[4];
#pragma unroll
        for (int hk = 0; hk < 2; ++hk) {
            union { fp16x2 h2[4]; half8 v; } u0, u1;
#pragma unroll
            for (int j = 0; j < 4; ++j) {
                u0.h2[j] = __builtin_amdgcn_cvt_pkrtz(p0[8 * hk + 2 * j], p0[8 * hk + 2 * j + 1]);
                u1.h2[j] = __builtin_amdgcn_cvt_pkrtz(p1[8 * hk + 2 * j], p1[8 * hk + 2 * j + 1]);
            }
            pf[hk]     = u0.v;   // km=0 -> kc 0,1
            pf[2 + hk] = u1.v;   // km=1 -> kc 2,3
        }

        // ---- O^T += V^T · P^T : D col=q=lq, row=d=(r&3)+8(r>>2)+4hi (+32*dc) ----
        const unsigned short* vb = lds_v[cur];
#pragma unroll
        for (int kc = 0; kc < 4; ++kc) {
            half8 vf0 = *(const half8*)&vb[lq * 64 + off[kc]];
            half8 vf1 = *(const half8*)&vb[(32 + lq) * 64 + off[kc]];
            acc0 = __builtin_amdgcn_mfma_f32_32x32x16_f16(vf0, pf[kc], acc0, 0, 0, 0);
            acc1 = __builtin_amdgcn_mfma_f32_32x32x16_f16(vf1, pf[kc], acc1, 0, 0, 0);
        }

        __syncthreads();   // stage(t+1) complete + all reads of cur done
    }

    // ---- epilogue ----
    float inv = 1.0f / lrow;
    const int qg = q0 + wq * 32 + lq;
    float* orow = Og + (size_t)qg * 512;
#pragma unroll
    for (int a = 0; a < 4; ++a) {
        f32x4 o0, o1;
#pragma unroll
        for (int i = 0; i < 4; ++i) {
            o0[i] = acc0[4 * a + i] * inv;
            o1[i] = acc1[4 * a + i] * inv;
        }
        *(f32x4*)(orow + 8 * a + 4 * hi)      = o0;
        *(f32x4*)(orow + 32 + 8 * a + 4 * hi) = o1;
    }
}

// ================= fallback (round-1 kernel, passes) =================
__device__ __forceinline__ unsigned short f2bf(float f) {
    union { float f; unsigned u; } v; v.f = f;
    unsigned u = v.u;
    u += 0x7fffu + ((u >> 16) & 1u);
    return (unsigned short)(u >> 16);
}

__global__ __launch_bounds__(128, 2)
void attn_v1_kernel(const float* __restrict__ Q, const float* __restrict__ K,
                    const float* __restrict__ V, float* __restrict__ O) {
    __shared__ __align__(16) unsigned short lds_q[64 * 64];
    __shared__ __align__(16) unsigned short lds_k[64 * 64];
    __shared__ __align__(16) unsigned short lds_v[64 * 64];

    const int tid = threadIdx.x, lane = tid & 63, wv = tid >> 6;
    const int lq = lane & 15, g = lane >> 4;
    const int bid = blockIdx.x, xcd = bid & 7, slot = bid >> 3;
    const int qt = slot & 31;
    const int bh = ((slot >> 5) << 3) | xcd;
    const int b = bh >> 3, h = bh & 7;
    const size_t base = ((size_t)b * 2048 * 8 + (size_t)h) * 64;
    const float* Qg = Q + base; const float* Kg = K + base;
    const float* Vg = V + base; float* Og = O + base;
    const int q0 = qt * 64;
    const float S2E = 0.125f * 1.44269504088896341f;

#pragma unroll
    for (int p = 0; p < 16; ++p) {
        int r = (tid >> 5) + p * 4, e = (tid & 31) * 2;
        const float* src = Qg + (size_t)(q0 + r) * 512 + e;
        unsigned pk = (unsigned)f2bf(src[0]) | ((unsigned)f2bf(src[1]) << 16);
        *(unsigned*)&lds_q[(r * 64 + e) ^ ((r & 7) << 3)] = pk;
    }
    __syncthreads();
    short8 qf[2][2];
#pragma unroll
    for (int qc = 0; qc < 2; ++qc) {
        int row = wv * 32 + qc * 16 + lq;
#pragma unroll
        for (int j = 0; j < 2; ++j)
            qf[qc][j] = *(const short8*)&lds_q[(row * 64 + j * 32 + g * 8) ^ ((row & 7) << 3)];
    }
    f32x4 acc[2][4];
#pragma unroll
    for (int qc = 0; qc < 2; ++qc)
#pragma unroll
        for (int dc = 0; dc < 4; ++dc) acc[qc][dc] = (f32x4){0.f, 0.f, 0.f, 0.f};
    float mrow[2] = {-1e30f, -1e30f}, lrow[2] = {0.f, 0.f};

    for (int t = 0; t < 32; ++t) {
        const int kv0 = t * 64;
        __syncthreads();
#pragma unroll
        for (int p = 0; p < 16; ++p) {
            int r = (tid >> 5) + p * 4, e = (tid & 31) * 2;
            const float* src = Kg + (size_t)(kv0 + r) * 512 + e;
            unsigned pk = (unsigned)f2bf(src[0]) | ((unsigned)f2bf(src[1]) << 16);
            *(unsigned*)&lds_k[(r * 64 + e) ^ ((r & 7) << 3)] = pk;
        }
#pragma unroll
        for (int p = 0; p < 16; ++p) {
            int d = tid & 63, kv = (p * 2 + (tid >> 6)) * 2;
            float v0 = Vg[(size_t)(kv0 + kv) * 512 + d];
            float v1 = Vg[(size_t)(kv0 + kv + 1) * 512 + d];
            union { _Float16 hh[2]; unsigned u; } pk;
            pk.hh[0] = (_Float16)v0; pk.hh[1] = (_Float16)v1;
            *(unsigned*)&lds_v[(d * 64 + kv) ^ ((d & 15) << 2)] = pk.u;
        }
        __syncthreads();
        f32x4 sfr[2][4];
#pragma unroll
        for (int kc = 0; kc < 4; ++kc) {
            int row = kc * 16 + lq;
            short8 kf0 = *(const short8*)&lds_k[(row * 64 + 0 + g * 8) ^ ((row & 7) << 3)];
            short8 kf1 = *(const short8*)&lds_k[(row * 64 + 32 + g * 8) ^ ((row & 7) << 3)];
#pragma unroll
            for (int qc = 0; qc < 2; ++qc) {
                f32x4 s = __builtin_amdgcn_mfma_f32_16x16x32_bf16(kf0, qf[qc][0], (f32x4){0.f,0.f,0.f,0.f}, 0, 0, 0);
                s = __builtin_amdgcn_mfma_f32_16x16x32_bf16(kf1, qf[qc][1], s, 0, 0, 0);
                sfr[qc][kc] = s;
            }
        }
        half4 pfv[2][4];
#pragma unroll
        for (int qc = 0; qc < 2; ++qc) {
            float smax = -1e30f;
#pragma unroll
            for (int kc = 0; kc < 4; ++kc)
#pragma unroll
                for (int r = 0; r < 4; ++r) smax = fmaxf(smax, sfr[qc][kc][r]);
            smax = fmaxf(smax, __shfl_xor(smax, 16));
            smax = fmaxf(smax, __shfl_xor(smax, 32));
            float mn = fmaxf(mrow[qc], smax);
            float alpha = __builtin_amdgcn_exp2f((mrow[qc] - mn) * S2E);
            mrow[qc] = mn;
            float msc = mn * S2E, psum = 0.f;
#pragma unroll
            for (int kc = 0; kc < 4; ++kc)
#pragma unroll
                for (int r = 0; r < 4; ++r) {
                    float p = __builtin_amdgcn_exp2f(sfr[qc][kc][r] * S2E - msc);
                    psum += p;
                    pfv[qc][kc][r] = (_Float16)p;
                }
            psum += __shfl_xor(psum, 16);
            psum += __shfl_xor(psum, 32);
            lrow[qc] = lrow[qc] * alpha + psum;
#pragma unroll
            for (int dc = 0; dc < 4; ++dc) acc[qc][dc] *= alpha;
        }
#pragma unroll
        for (int dc = 0; dc < 4; ++dc) {
            int dd = dc * 16 + lq;
#pragma unroll
            for (int kc = 0; kc < 4; ++kc) {
                half4 vf = *(const half4*)&lds_v[(dd * 64 + kc * 16 + g * 4) ^ ((dd & 15) << 2)];
                acc[0][dc] = __builtin_amdgcn_mfma_f32_16x16x16f16(vf, pfv[0][kc], acc[0][dc], 0, 0, 0);
                acc[1][dc] = __builtin_amdgcn_mfma_f32_16x16x16f16(vf, pfv[1][kc], acc[1][dc], 0, 0, 0);
            }
        }
    }
#pragma unroll
    for (int qc = 0; qc < 2; ++qc) {
        float inv = 1.f / lrow[qc];
        int qrow = q0 + wv * 32 + qc * 16 + lq;
#pragma unroll
        for (int dc = 0; dc < 4; ++dc) {
            f32x4 o = acc[qc][dc] * inv;
            *(f32x4*)(Og + (size_t)qrow * 512 + dc * 16 + g * 4) = o;
        }
    }
}

extern "C" void kernel_launch(void* const* d_in, const int* in_sizes, int n_in,
                              void* d_out, int out_size, void* d_ws, size_t ws_size,
                              hipStream_t stream) {
    const float* Q = (const float*)d_in[0];
    const float* K = (const float*)d_in[1];
    const float* V = (const float*)d_in[2];
    float* O = (float*)d_out;

    const size_t per = (size_t)32 * 2048 * 64;           // elements per tensor
    const size_t need = 3 * per * sizeof(unsigned short); // 24 MB
    if (ws_size >= need) {
        unsigned short* wsQ = (unsigned short*)d_ws;
        unsigned short* wsK = wsQ + per;
        unsigned short* wsV = wsK + per;
        cvt_rows_kernel<<<dim3(4096), dim3(256), 0, stream>>>(Q, wsQ);
        cvt_rows_kernel<<<dim3(4096), dim3(256), 0, stream>>>(K, wsK);
        cvt_vT_kernel  <<<dim3(4096), dim3(256), 0, stream>>>(V, wsV);
        attn_v2_kernel <<<dim3(512),  dim3(256), 0, stream>>>(wsQ, wsK, wsV, O);
    } else {
        attn_v1_kernel <<<dim3(1024), dim3(128), 0, stream>>>(Q, K, V, O);
    }
}

// Round 4
// 71.133 us; speedup vs baseline: 1.4197x; 1.0584x over previous
//
#include <hip/hip_runtime.h>

typedef __attribute__((ext_vector_type(4)))  float    f32x4;
typedef __attribute__((ext_vector_type(16))) float    f32x16;
typedef __attribute__((ext_vector_type(8)))  _Float16 half8;
typedef __attribute__((ext_vector_type(2)))  __fp16   fp16x2;
typedef __attribute__((ext_vector_type(4)))  _Float16 half4;
typedef __attribute__((ext_vector_type(8)))  short    short8;

#define SCL2E 0.18033688011112042f   // (1/8) * log2(e)

__device__ __forceinline__ unsigned short f2h_bits(float x) {
    union { _Float16 h; unsigned short u; } c;
    c.h = (_Float16)x;
    return c.u;
}

__device__ __forceinline__ void gl_lds16(const unsigned short* g, unsigned short* l) {
    __builtin_amdgcn_global_load_lds((const __attribute__((address_space(1))) void*)g,
                                     (__attribute__((address_space(3))) void*)l, 16, 0, 0);
}

// ---------------- prepass: Q and K rows -> f16, perm(bit2<->bit3 of e) + swizzle ----------------
// in:  src[b][row][h][e] f32   out: dst[bh][row][perm_swz(e)] f16-bits
__global__ __launch_bounds__(256)
void cvt_qk_kernel(const float* __restrict__ Q, const float* __restrict__ K,
                   unsigned short* __restrict__ wsQ, unsigned short* __restrict__ wsK) {
    int bid = blockIdx.x;                          // 0..8191
    const float* src          = (bid < 4096) ? Q   : K;
    unsigned short* dst       = (bid < 4096) ? wsQ : wsK;
    int t   = (bid & 4095) * 256 + threadIdx.x;    // 1,048,576 per tensor
    int eg  = t & 15;                              // 4-element group within row
    int gr  = t >> 4;                              // bh*2048 + row
    int row = gr & 2047, bh = gr >> 11;
    int b = bh >> 3, h = bh & 7;
    const float* sp = src + (((size_t)b * 2048 + row) * 8 + h) * 64 + eg * 4;
    f32x4 v = *(const f32x4*)sp;
    int cg = (eg & ~3) | ((eg & 1) << 1) | ((eg >> 1) & 1);   // swap e bits 2,3
    cg ^= (row & 7) << 1;                                     // bank swizzle (e bits 3..5)
    union { unsigned short s[4]; unsigned long long u; } o;
    o.s[0] = f2h_bits(v[0]); o.s[1] = f2h_bits(v[1]);
    o.s[2] = f2h_bits(v[2]); o.s[3] = f2h_bits(v[3]);
    *(unsigned long long*)(dst + (size_t)gr * 64 + cg * 4) = o.u;
}

// ---------------- prepass: V -> f16 transposed [bh][d][kv], perm+swizzle on kv ----------------
__global__ __launch_bounds__(256)
void cvt_vT_kernel(const float* __restrict__ src, unsigned short* __restrict__ dst) {
    int t   = blockIdx.x * 256 + threadIdx.x;
    int d   = t & 63;
    int g   = t >> 6;
    int kv4 = g & 511, bh = g >> 9;
    int b = bh >> 3, h = bh & 7;
    int kv = kv4 * 4;
    const float* sp = src + (((size_t)b * 2048 + kv) * 8 + h) * 64 + d;
    float v0 = sp[0], v1 = sp[512], v2 = sp[1024], v3 = sp[1536];
    int lg  = kv4 & 15;
    int lgp = (lg & ~3) | ((lg & 1) << 1) | ((lg >> 1) & 1);
    lgp ^= (d & 7) << 1;
    union { unsigned short s[4]; unsigned long long u; } o;
    o.s[0] = f2h_bits(v0); o.s[1] = f2h_bits(v1);
    o.s[2] = f2h_bits(v2); o.s[3] = f2h_bits(v3);
    *(unsigned long long*)(dst + ((size_t)bh * 64 + d) * 2048 + (kv4 & ~15) * 4 + lgp * 4) = o.u;
}

// ---------------- main: 8 waves = 4 q-chunks x 2 kv-halves, 32x32 swapped-QK^T ----------------
__global__ __launch_bounds__(512, 4)
void attn_v3_kernel(const unsigned short* __restrict__ wsQ,
                    const unsigned short* __restrict__ wsK,
                    const unsigned short* __restrict__ wsV,
                    float* __restrict__ O) {
    // [buf][K=0/V=1][kh][64*64]  = 64 KB
    __shared__ __align__(16) unsigned short lds[2][2][2][4096];

    const int tid  = threadIdx.x;
    const int lane = tid & 63;
    const int w    = tid >> 6;          // wave 0..7
    const int qw   = w & 3;             // q chunk
    const int kh   = w >> 2;            // kv half
    const int lq   = lane & 31;
    const int hi   = lane >> 5;
    const int swz  = (lq & 7) << 3;

    const int bid = blockIdx.x;
    const int xcd = bid & 7, slot = bid >> 3;
    const int qt  = slot & 15;
    const int bh  = ((slot >> 4) << 3) | xcd;   // XCD-local bh
    const int q0  = qt * 128;

    const unsigned short* Ksrc = wsK + (size_t)bh * 2048 * 64;
    const unsigned short* Vsrc = wsV + (size_t)bh * 64 * 2048;
    float* Og = O + ((size_t)(bh >> 3) * 2048 * 8 + (bh & 7)) * 64;

    int off[4];
#pragma unroll
    for (int ks = 0; ks < 4; ++ks) off[ks] = (ks * 16 + hi * 8) ^ swz;

    // stage tile 0 (both kv halves): K and V, 32 KB total, 1 chunk per thread per tensor-half
    {
        const size_t kvb0 = 0, kvb1 = 1024;
        gl_lds16(Ksrc + kvb0 * 64 + tid * 8, &lds[0][0][0][tid * 8]);
        gl_lds16(Vsrc + (size_t)(tid >> 3) * 2048 + kvb0 + (tid & 7) * 8, &lds[0][1][0][tid * 8]);
        gl_lds16(Ksrc + kvb1 * 64 + tid * 8, &lds[0][0][1][tid * 8]);
        gl_lds16(Vsrc + (size_t)(tid >> 3) * 2048 + kvb1 + (tid & 7) * 8, &lds[0][1][1][tid * 8]);
    }

    // Q fragments: direct from pre-permuted ws (once)
    half8 qf[4];
    {
        const unsigned short* Qp = wsQ + ((size_t)bh * 2048 + q0 + qw * 32 + lq) * 64;
#pragma unroll
        for (int ks = 0; ks < 4; ++ks) qf[ks] = *(const half8*)&Qp[off[ks]];
    }

    f32x16 acc0 = {0.f,0.f,0.f,0.f,0.f,0.f,0.f,0.f,0.f,0.f,0.f,0.f,0.f,0.f,0.f,0.f};
    f32x16 acc1 = acc0;
    float mrow = -1e30f, lrow = 0.f;

    __syncthreads();

    for (int t = 0; t < 16; ++t) {
        const int cur = t & 1;
        if (t + 1 < 16) {   // stage next tile pair into other buffer
            const int nxt = cur ^ 1;
            const size_t kv0 = (size_t)(t + 1) * 64;
            const size_t kvb0 = kv0, kvb1 = 1024 + kv0;
            gl_lds16(Ksrc + kvb0 * 64 + tid * 8, &lds[nxt][0][0][tid * 8]);
            gl_lds16(Vsrc + (size_t)(tid >> 3) * 2048 + kvb0 + (tid & 7) * 8, &lds[nxt][1][0][tid * 8]);
            gl_lds16(Ksrc + kvb1 * 64 + tid * 8, &lds[nxt][0][1][tid * 8]);
            gl_lds16(Vsrc + (size_t)(tid >> 3) * 2048 + kvb1 + (tid & 7) * 8, &lds[nxt][1][1][tid * 8]);
        }

        // ---- S^T = K · Q^T : D col=q=lq, row=kv_local=(r&3)+8(r>>2)+4hi ----
        const unsigned short* kb = &lds[cur][0][kh][0];
        f32x16 s0 = {0.f,0.f,0.f,0.f,0.f,0.f,0.f,0.f,0.f,0.f,0.f,0.f,0.f,0.f,0.f,0.f};
        f32x16 s1 = s0;
        __builtin_amdgcn_s_setprio(1);
#pragma unroll
        for (int ks = 0; ks < 4; ++ks) {
            half8 kf0 = *(const half8*)&kb[lq * 64 + off[ks]];
            half8 kf1 = *(const half8*)&kb[(32 + lq) * 64 + off[ks]];
            s0 = __builtin_amdgcn_mfma_f32_32x32x16_f16(kf0, qf[ks], s0, 0, 0, 0);
            s1 = __builtin_amdgcn_mfma_f32_32x32x16_f16(kf1, qf[ks], s1, 0, 0, 0);
        }
        __builtin_amdgcn_s_setprio(0);

        // ---- online softmax: tree max (depth 5) ----
        float mx[16];
#pragma unroll
        for (int i = 0; i < 16; ++i) mx[i] = fmaxf(s0[i], s1[i]);
#pragma unroll
        for (int st = 8; st >= 1; st >>= 1)
#pragma unroll
            for (int i = 0; i < st; ++i) mx[i] = fmaxf(mx[i], mx[i + st]);
        float smax = fmaxf(mx[0], __shfl_xor(mx[0], 32));

        if (!__all(smax - mrow <= 22.0f)) {       // defer-max: p bounded by ~2^4
            float mnew  = fmaxf(mrow, smax);
            float alpha = __builtin_amdgcn_exp2f((mrow - mnew) * SCL2E);
            mrow = mnew;
            lrow *= alpha;
            acc0 *= alpha;
            acc1 *= alpha;
        }
        const float msc = mrow * SCL2E;

        // ---- exp -> f16 pack -> pair-sum (keeps f32 P live range short) ----
        half8 pf[4];
        float psum = 0.f;
#pragma unroll
        for (int hm = 0; hm < 2; ++hm) {
            const f32x16& sb = hm ? s1 : s0;
#pragma unroll
            for (int hk = 0; hk < 2; ++hk) {
                union { fp16x2 h2[4]; half8 v; } u;
                float g0, g1;
#pragma unroll
                for (int j = 0; j < 4; ++j) {
                    float e0 = __builtin_amdgcn_exp2f(sb[8 * hk + 2 * j]     * SCL2E - msc);
                    float e1 = __builtin_amdgcn_exp2f(sb[8 * hk + 2 * j + 1] * SCL2E - msc);
                    u.h2[j] = __builtin_amdgcn_cvt_pkrtz(e0, e1);
                    float gj = e0 + e1;
                    if (j == 0) g0 = gj; else if (j == 1) g1 = gj;
                    else if (j == 2) g0 += gj; else g1 += gj;
                }
                pf[2 * hm + hk] = u.v;
                psum += g0 + g1;
            }
        }
        psum += __shfl_xor(psum, 32);
        lrow += psum;

        // ---- O^T += V^T · P^T ----
        const unsigned short* vb = &lds[cur][1][kh][0];
        __builtin_amdgcn_s_setprio(1);
#pragma unroll
        for (int kc = 0; kc < 4; ++kc) {
            half8 vf0 = *(const half8*)&vb[lq * 64 + off[kc]];
            half8 vf1 = *(const half8*)&vb[(32 + lq) * 64 + off[kc]];
            acc0 = __builtin_amdgcn_mfma_f32_32x32x16_f16(vf0, pf[kc], acc0, 0, 0, 0);
            acc1 = __builtin_amdgcn_mfma_f32_32x32x16_f16(vf1, pf[kc], acc1, 0, 0, 0);
        }
        __builtin_amdgcn_s_setprio(0);

        __syncthreads();   // stage(t+1) landed + all reads of cur done
    }

    // ---- merge kv halves via LDS (reuse tile memory) ----
    float* mlds = (float*)&lds[0][0][0][0];   // need 4*64*36*4 = 36,864 B <= 64 KB
    const int mslot = (qw * 64 + lane) * 36;
    if (kh) {
        float* dst = mlds + mslot;
#pragma unroll
        for (int a = 0; a < 4; ++a) {
            *(f32x4*)(dst + 4 * a)      = (f32x4){acc0[4*a], acc0[4*a+1], acc0[4*a+2], acc0[4*a+3]};
            *(f32x4*)(dst + 16 + 4 * a) = (f32x4){acc1[4*a], acc1[4*a+1], acc1[4*a+2], acc1[4*a+3]};
        }
        dst[32] = mrow; dst[33] = lrow;
    }
    __syncthreads();
    if (!kh) {
        const float* src = mlds + mslot;
        float m1 = src[32], l1 = src[33];
        float m  = fmaxf(mrow, m1);
        float a0 = __builtin_amdgcn_exp2f((mrow - m) * SCL2E);
        float a1 = __builtin_amdgcn_exp2f((m1   - m) * SCL2E);
        float inv = 1.0f / (lrow * a0 + l1 * a1);
        float c0 = a0 * inv, c1 = a1 * inv;

        const int qg = q0 + qw * 32 + lq;
        float* orow = Og + (size_t)qg * 512;
#pragma unroll
        for (int a = 0; a < 4; ++a) {
            f32x4 p0 = *(const f32x4*)(src + 4 * a);
            f32x4 p1 = *(const f32x4*)(src + 16 + 4 * a);
            f32x4 o0, o1;
#pragma unroll
            for (int i = 0; i < 4; ++i) {
                o0[i] = acc0[4 * a + i] * c0 + p0[i] * c1;
                o1[i] = acc1[4 * a + i] * c0 + p1[i] * c1;
            }
            *(f32x4*)(orow + 8 * a + 4 * hi)      = o0;
            *(f32x4*)(orow + 32 + 8 * a + 4 * hi) = o1;
        }
    }
}

// ================= fallback (round-1 kernel, passes) =================
__device__ __forceinline__ unsigned short f2bf(float f) {
    union { float f; unsigned u; } v; v.f = f;
    unsigned u = v.u;
    u += 0x7fffu + ((u >> 16) & 1u);
    return (unsigned short)(u >> 16);
}

__global__ __launch_bounds__(128, 2)
void attn_v1_kernel(const float* __restrict__ Q, const float* __restrict__ K,
                    const float* __restrict__ V, float* __restrict__ O) {
    __shared__ __align__(16) unsigned short lds_q[64 * 64];
    __shared__ __align__(16) unsigned short lds_k[64 * 64];
    __shared__ __align__(16) unsigned short lds_v[64 * 64];

    const int tid = threadIdx.x, lane = tid & 63, wv = tid >> 6;
    const int lq = lane & 15, g = lane >> 4;
    const int bid = blockIdx.x, xcd = bid & 7, slot = bid >> 3;
    const int qt = slot & 31;
    const int bh = ((slot >> 5) << 3) | xcd;
    const int b = bh >> 3, h = bh & 7;
    const size_t base = ((size_t)b * 2048 * 8 + (size_t)h) * 64;
    const float* Qg = Q + base; const float* Kg = K + base;
    const float* Vg = V + base; float* Og = O + base;
    const int q0 = qt * 64;
    const float S2E = 0.125f * 1.44269504088896341f;

#pragma unroll
    for (int p = 0; p < 16; ++p) {
        int r = (tid >> 5) + p * 4, e = (tid & 31) * 2;
        const float* src = Qg + (size_t)(q0 + r) * 512 + e;
        unsigned pk = (unsigned)f2bf(src[0]) | ((unsigned)f2bf(src[1]) << 16);
        *(unsigned*)&lds_q[(r * 64 + e) ^ ((r & 7) << 3)] = pk;
    }
    __syncthreads();
    short8 qf[2][2];
#pragma unroll
    for (int qc = 0; qc < 2; ++qc) {
        int row = wv * 32 + qc * 16 + lq;
#pragma unroll
        for (int j = 0; j < 2; ++j)
            qf[qc][j] = *(const short8*)&lds_q[(row * 64 + j * 32 + g * 8) ^ ((row & 7) << 3)];
    }
    f32x4 acc[2][4];
#pragma unroll
    for (int qc = 0; qc < 2; ++qc)
#pragma unroll
        for (int dc = 0; dc < 4; ++dc) acc[qc][dc] = (f32x4){0.f, 0.f, 0.f, 0.f};
    float mrow[2] = {-1e30f, -1e30f}, lrow[2] = {0.f, 0.f};

    for (int t = 0; t < 32; ++t) {
        const int kv0 = t * 64;
        __syncthreads();
#pragma unroll
        for (int p = 0; p < 16; ++p) {
            int r = (tid >> 5) + p * 4, e = (tid & 31) * 2;
            const float* src = Kg + (size_t)(kv0 + r) * 512 + e;
            unsigned pk = (unsigned)f2bf(src[0]) | ((unsigned)f2bf(src[1]) << 16);
            *(unsigned*)&lds_k[(r * 64 + e) ^ ((r & 7) << 3)] = pk;
        }
#pragma unroll
        for (int p = 0; p < 16; ++p) {
            int d = tid & 63, kv = (p * 2 + (tid >> 6)) * 2;
            float v0 = Vg[(size_t)(kv0 + kv) * 512 + d];
            float v1 = Vg[(size_t)(kv0 + kv + 1) * 512 + d];
            union { _Float16 hh[2]; unsigned u; } pk;
            pk.hh[0] = (_Float16)v0; pk.hh[1] = (_Float16)v1;
            *(unsigned*)&lds_v[(d * 64 + kv) ^ ((d & 15) << 2)] = pk.u;
        }
        __syncthreads();
        f32x4 sfr[2][4];
#pragma unroll
        for (int kc = 0; kc < 4; ++kc) {
            int row = kc * 16 + lq;
            short8 kf0 = *(const short8*)&lds_k[(row * 64 + 0 + g * 8) ^ ((row & 7) << 3)];
            short8 kf1 = *(const short8*)&lds_k[(row * 64 + 32 + g * 8) ^ ((row & 7) << 3)];
#pragma unroll
            for (int qc = 0; qc < 2; ++qc) {
                f32x4 s = __builtin_amdgcn_mfma_f32_16x16x32_bf16(kf0, qf[qc][0], (f32x4){0.f,0.f,0.f,0.f}, 0, 0, 0);
                s = __builtin_amdgcn_mfma_f32_16x16x32_bf16(kf1, qf[qc][1], s, 0, 0, 0);
                sfr[qc][kc] = s;
            }
        }
        half4 pfv[2][4];
#pragma unroll
        for (int qc = 0; qc < 2; ++qc) {
            float smax = -1e30f;
#pragma unroll
            for (int kc = 0; kc < 4; ++kc)
#pragma unroll
                for (int r = 0; r < 4; ++r) smax = fmaxf(smax, sfr[qc][kc][r]);
            smax = fmaxf(smax, __shfl_xor(smax, 16));
            smax = fmaxf(smax, __shfl_xor(smax, 32));
            float mn = fmaxf(mrow[qc], smax);
            float alpha = __builtin_amdgcn_exp2f((mrow[qc] - mn) * S2E);
            mrow[qc] = mn;
            float msc = mn * S2E, psum = 0.f;
#pragma unroll
            for (int kc = 0; kc < 4; ++kc)
#pragma unroll
                for (int r = 0; r < 4; ++r) {
                    float p = __builtin_amdgcn_exp2f(sfr[qc][kc][r] * S2E - msc);
                    psum += p;
                    pfv[qc][kc][r] = (_Float16)p;
                }
            psum += __shfl_xor(psum, 16);
            psum += __shfl_xor(psum, 32);
            lrow[qc] = lrow[qc] * alpha + psum;
#pragma unroll
            for (int dc = 0; dc < 4; ++dc) acc[qc][dc] *= alpha;
        }
#pragma unroll
        for (int dc = 0; dc < 4; ++dc) {
            int dd = dc * 16 + lq;
#pragma unroll
            for (int kc = 0; kc < 4; ++kc) {
                half4 vf = *(const half4*)&lds_v[(dd * 64 + kc * 16 + g * 4) ^ ((dd & 15) << 2)];
                acc[0][dc] = __builtin_amdgcn_mfma_f32_16x16x16f16(vf, pfv[0][kc], acc[0][dc], 0, 0, 0);
                acc[1][dc] = __builtin_amdgcn_mfma_f32_16x16x16f16(vf, pfv[1][kc], acc[1][dc], 0, 0, 0);
            }
        }
    }
#pragma unroll
    for (int qc = 0; qc < 2; ++qc) {
        float inv = 1.f / lrow[qc];
        int qrow = q0 + wv * 32 + qc * 16 + lq;
#pragma unroll
        for (int dc = 0; dc < 4; ++dc) {
            f32x4 o = acc[qc][dc] * inv;
            *(f32x4*)(Og + (size_t)qrow * 512 + dc * 16 + g * 4) = o;
        }
    }
}

extern "C" void kernel_launch(void* const* d_in, const int* in_sizes, int n_in,
                              void* d_out, int out_size, void* d_ws, size_t ws_size,
                              hipStream_t stream) {
    const float* Q = (const float*)d_in[0];
    const float* K = (const float*)d_in[1];
    const float* V = (const float*)d_in[2];
    float* O = (float*)d_out;

    const size_t per = (size_t)32 * 2048 * 64;            // elements per tensor
    const size_t need = 3 * per * sizeof(unsigned short); // 24 MB
    if (ws_size >= need) {
        unsigned short* wsQ = (unsigned short*)d_ws;
        unsigned short* wsK = wsQ + per;
        unsigned short* wsV = wsK + per;
        cvt_qk_kernel<<<dim3(8192), dim3(256), 0, stream>>>(Q, K, wsQ, wsK);
        cvt_vT_kernel<<<dim3(4096), dim3(256), 0, stream>>>(V, wsV);
        attn_v3_kernel<<<dim3(512), dim3(512), 0, stream>>>(wsQ, wsK, wsV, O);
    } else {
        attn_v1_kernel<<<dim3(1024), dim3(128), 0, stream>>>(Q, K, V, O);
    }
}

// Round 5
// 59.006 us; speedup vs baseline: 1.7115x; 1.2055x over previous
//
#include <hip/hip_runtime.h>

typedef __attribute__((ext_vector_type(4)))  float    f32x4;
typedef __attribute__((ext_vector_type(16))) float    f32x16;
typedef __attribute__((ext_vector_type(8)))  _Float16 half8;
typedef __attribute__((ext_vector_type(2)))  __fp16   fp16x2;
typedef __attribute__((ext_vector_type(4)))  _Float16 half4;
typedef __attribute__((ext_vector_type(8)))  short    short8;

#define SCL2E 0.18033688011112042f   // (1/8) * log2(e)  — folded into Q

__device__ __forceinline__ unsigned short f2h_bits(float x) {
    union { _Float16 h; unsigned short u; } c;
    c.h = (_Float16)x;
    return c.u;
}

__device__ __forceinline__ void gl_lds16(const unsigned short* g, unsigned short* l) {
    __builtin_amdgcn_global_load_lds((const __attribute__((address_space(1))) void*)g,
                                     (__attribute__((address_space(3))) void*)l, 16, 0, 0);
}

// ---------------- prepass (fused): K rows + V transpose -> f16, perm + swizzle ----------------
__global__ __launch_bounds__(256)
void cvt_kv_kernel(const float* __restrict__ K, const float* __restrict__ V,
                   unsigned short* __restrict__ wsK, unsigned short* __restrict__ wsV) {
    int bid = blockIdx.x;                           // 0..8191
    if (bid < 4096) {
        // K: [b][row][h][e] -> wsK[bh][row][perm_swz(e)]
        int t   = bid * 256 + threadIdx.x;
        int eg  = t & 15;
        int gr  = t >> 4;
        int row = gr & 2047, bh = gr >> 11;
        int b = bh >> 3, h = bh & 7;
        const float* sp = K + (((size_t)b * 2048 + row) * 8 + h) * 64 + eg * 4;
        f32x4 v = *(const f32x4*)sp;
        int cg = (eg & ~3) | ((eg & 1) << 1) | ((eg >> 1) & 1);   // swap e bits 2,3
        cg ^= (row & 7) << 1;                                     // bank swizzle
        union { unsigned short s[4]; unsigned long long u; } o;
        o.s[0] = f2h_bits(v[0]); o.s[1] = f2h_bits(v[1]);
        o.s[2] = f2h_bits(v[2]); o.s[3] = f2h_bits(v[3]);
        *(unsigned long long*)(wsK + (size_t)gr * 64 + cg * 4) = o.u;
    } else {
        // V -> wsV[bh][d][perm_swz(kv)] (transposed)
        int t   = (bid - 4096) * 256 + threadIdx.x;
        int d   = t & 63;
        int g   = t >> 6;
        int kv4 = g & 511, bh = g >> 9;
        int b = bh >> 3, h = bh & 7;
        int kv = kv4 * 4;
        const float* sp = V + (((size_t)b * 2048 + kv) * 8 + h) * 64 + d;
        float v0 = sp[0], v1 = sp[512], v2 = sp[1024], v3 = sp[1536];
        int lg  = kv4 & 15;
        int lgp = (lg & ~3) | ((lg & 1) << 1) | ((lg >> 1) & 1);
        lgp ^= (d & 7) << 1;
        union { unsigned short s[4]; unsigned long long u; } o;
        o.s[0] = f2h_bits(v0); o.s[1] = f2h_bits(v1);
        o.s[2] = f2h_bits(v2); o.s[3] = f2h_bits(v3);
        *(unsigned long long*)(wsV + ((size_t)bh * 64 + d) * 2048 + (kv4 & ~15) * 4 + lgp * 4) = o.u;
    }
}

// ---------------- main: 8 waves = 4 q-chunks x 2 kv-halves, no-max online softmax ----------------
__global__ __launch_bounds__(512, 4)
void attn_v4_kernel(const float* __restrict__ Q,
                    const unsigned short* __restrict__ wsK,
                    const unsigned short* __restrict__ wsV,
                    float* __restrict__ O) {
    __shared__ __align__(16) unsigned short lds[2][2][2][4096];   // 64 KB  [buf][K/V][kh]
    __shared__ __align__(16) unsigned short lds_q[128 * 64];      // 16 KB

    const int tid  = threadIdx.x;
    const int lane = tid & 63;
    const int w    = tid >> 6;          // wave 0..7
    const int qw   = w & 3;             // q chunk
    const int kh   = w >> 2;            // kv half
    const int lq   = lane & 31;
    const int hi   = lane >> 5;
    const int swz  = (lq & 7) << 3;

    const int bid = blockIdx.x;
    const int xcd = bid & 7, slot = bid >> 3;
    const int qt  = slot & 15;
    const int bh  = ((slot >> 4) << 3) | xcd;   // XCD-local bh
    const int q0  = qt * 128;
    const int b   = bh >> 3, h = bh & 7;

    const unsigned short* Ksrc = wsK + (size_t)bh * 2048 * 64;
    const unsigned short* Vsrc = wsV + (size_t)bh * 64 * 2048;
    float* Og = O + ((size_t)b * 2048 * 8 + (size_t)h) * 64;

    // ---- stage Q (scale folded) into lds_q, perm+swizzled; coalesced f32x4 loads ----
#pragma unroll
    for (int p = 0; p < 4; ++p) {
        int t  = tid + 512 * p;          // 0..2047
        int eg = t & 15;
        int r  = t >> 4;                 // 0..127
        const float* sp = Q + (((size_t)b * 2048 + q0 + r) * 8 + h) * 64 + eg * 4;
        f32x4 v = *(const f32x4*)sp;
        int cg = (eg & ~3) | ((eg & 1) << 1) | ((eg >> 1) & 1);
        cg ^= (r & 7) << 1;
        union { unsigned short s[4]; unsigned long long u; } o;
        o.s[0] = f2h_bits(v[0] * SCL2E); o.s[1] = f2h_bits(v[1] * SCL2E);
        o.s[2] = f2h_bits(v[2] * SCL2E); o.s[3] = f2h_bits(v[3] * SCL2E);
        *(unsigned long long*)&lds_q[r * 64 + cg * 4] = o.u;
    }

    // stage tile 0 (both kv halves) via DMA
    {
        const size_t kvb0 = 0, kvb1 = 1024;
        gl_lds16(Ksrc + kvb0 * 64 + tid * 8, &lds[0][0][0][tid * 8]);
        gl_lds16(Vsrc + (size_t)(tid >> 3) * 2048 + kvb0 + (tid & 7) * 8, &lds[0][1][0][tid * 8]);
        gl_lds16(Ksrc + kvb1 * 64 + tid * 8, &lds[0][0][1][tid * 8]);
        gl_lds16(Vsrc + (size_t)(tid >> 3) * 2048 + kvb1 + (tid & 7) * 8, &lds[0][1][1][tid * 8]);
    }
    __syncthreads();

    int off[4];
#pragma unroll
    for (int ks = 0; ks < 4; ++ks) off[ks] = (ks * 16 + hi * 8) ^ swz;

    half8 qf[4];
    {
        int qrow = qw * 32 + lq;
#pragma unroll
        for (int ks = 0; ks < 4; ++ks)
            qf[ks] = *(const half8*)&lds_q[qrow * 64 + off[ks]];
    }

    f32x16 acc0 = {0.f,0.f,0.f,0.f,0.f,0.f,0.f,0.f,0.f,0.f,0.f,0.f,0.f,0.f,0.f,0.f};
    f32x16 acc1 = acc0;
    float lrowA = 0.f, lrowB = 0.f;
    const fp16x2 vone = {(__fp16)1.0f, (__fp16)1.0f};

    for (int t = 0; t < 16; ++t) {
        const int cur = t & 1;
        if (t + 1 < 16) {
            const int nxt = cur ^ 1;
            const size_t kv0 = (size_t)(t + 1) * 64;
            const size_t kvb0 = kv0, kvb1 = 1024 + kv0;
            gl_lds16(Ksrc + kvb0 * 64 + tid * 8, &lds[nxt][0][0][tid * 8]);
            gl_lds16(Vsrc + (size_t)(tid >> 3) * 2048 + kvb0 + (tid & 7) * 8, &lds[nxt][1][0][tid * 8]);
            gl_lds16(Ksrc + kvb1 * 64 + tid * 8, &lds[nxt][0][1][tid * 8]);
            gl_lds16(Vsrc + (size_t)(tid >> 3) * 2048 + kvb1 + (tid & 7) * 8, &lds[nxt][1][1][tid * 8]);
        }

        // ---- S^T = K · Q^T : D col=q=lq, row=kv_local=(r&3)+8(r>>2)+4hi ----
        const unsigned short* kb = &lds[cur][0][kh][0];
        f32x16 s0 = {0.f,0.f,0.f,0.f,0.f,0.f,0.f,0.f,0.f,0.f,0.f,0.f,0.f,0.f,0.f,0.f};
        f32x16 s1 = s0;
        __builtin_amdgcn_s_setprio(1);
#pragma unroll
        for (int ks = 0; ks < 4; ++ks) {
            half8 kf0 = *(const half8*)&kb[lq * 64 + off[ks]];
            half8 kf1 = *(const half8*)&kb[(32 + lq) * 64 + off[ks]];
            s0 = __builtin_amdgcn_mfma_f32_32x32x16_f16(kf0, qf[ks], s0, 0, 0, 0);
            s1 = __builtin_amdgcn_mfma_f32_32x32x16_f16(kf1, qf[ks], s1, 0, 0, 0);
        }
        __builtin_amdgcn_s_setprio(0);

        // ---- p = exp2(s) directly (no max tracking); pack to f16; psum via fdot2 ----
        half8 pf[4];
        float pA = 0.f, pB = 0.f;
#pragma unroll
        for (int hm = 0; hm < 2; ++hm) {
            const f32x16& sb = hm ? s1 : s0;
#pragma unroll
            for (int hk = 0; hk < 2; ++hk) {
                union { fp16x2 h2[4]; half8 v; } u;
#pragma unroll
                for (int j = 0; j < 4; ++j) {
                    float e0 = __builtin_amdgcn_exp2f(sb[8 * hk + 2 * j]);
                    float e1 = __builtin_amdgcn_exp2f(sb[8 * hk + 2 * j + 1]);
                    u.h2[j] = __builtin_amdgcn_cvt_pkrtz(e0, e1);
#if __has_builtin(__builtin_amdgcn_fdot2)
                    if (hm == 0) pA = __builtin_amdgcn_fdot2(u.h2[j], vone, pA, false);
                    else         pB = __builtin_amdgcn_fdot2(u.h2[j], vone, pB, false);
#else
                    if (hm == 0) pA += e0 + e1; else pB += e0 + e1;
#endif
                }
                pf[2 * hm + hk] = u.v;
            }
        }
        lrowA += pA; lrowB += pB;

        // ---- O^T += V^T · P^T ----
        const unsigned short* vb = &lds[cur][1][kh][0];
        __builtin_amdgcn_s_setprio(1);
#pragma unroll
        for (int kc = 0; kc < 4; ++kc) {
            half8 vf0 = *(const half8*)&vb[lq * 64 + off[kc]];
            half8 vf1 = *(const half8*)&vb[(32 + lq) * 64 + off[kc]];
            acc0 = __builtin_amdgcn_mfma_f32_32x32x16_f16(vf0, pf[kc], acc0, 0, 0, 0);
            acc1 = __builtin_amdgcn_mfma_f32_32x32x16_f16(vf1, pf[kc], acc1, 0, 0, 0);
        }
        __builtin_amdgcn_s_setprio(0);

        __syncthreads();
    }

    // ---- epilogue: merge lane halves of l, then merge kv halves via LDS (plain add) ----
    float lrow = lrowA + lrowB;
    lrow += __shfl_xor(lrow, 32);

    float* mlds = (float*)&lds[0][0][0][0];   // 4*64*36*4 = 36,864 B
    const int mslot = (qw * 64 + lane) * 36;
    if (kh) {
        float* dst = mlds + mslot;
#pragma unroll
        for (int a = 0; a < 4; ++a) {
            *(f32x4*)(dst + 4 * a)      = (f32x4){acc0[4*a], acc0[4*a+1], acc0[4*a+2], acc0[4*a+3]};
            *(f32x4*)(dst + 16 + 4 * a) = (f32x4){acc1[4*a], acc1[4*a+1], acc1[4*a+2], acc1[4*a+3]};
        }
        dst[32] = lrow;
    }
    __syncthreads();
    if (!kh) {
        const float* src = mlds + mslot;
        float inv = 1.0f / (lrow + src[32]);

        const int qg = q0 + qw * 32 + lq;
        float* orow = Og + (size_t)qg * 512;
#pragma unroll
        for (int a = 0; a < 4; ++a) {
            f32x4 p0 = *(const f32x4*)(src + 4 * a);
            f32x4 p1 = *(const f32x4*)(src + 16 + 4 * a);
            f32x4 o0, o1;
#pragma unroll
            for (int i = 0; i < 4; ++i) {
                o0[i] = (acc0[4 * a + i] + p0[i]) * inv;
                o1[i] = (acc1[4 * a + i] + p1[i]) * inv;
            }
            *(f32x4*)(orow + 8 * a + 4 * hi)      = o0;
            *(f32x4*)(orow + 32 + 8 * a + 4 * hi) = o1;
        }
    }
}

// ================= fallback (round-1 kernel, passes) =================
__device__ __forceinline__ unsigned short f2bf(float f) {
    union { float f; unsigned u; } v; v.f = f;
    unsigned u = v.u;
    u += 0x7fffu + ((u >> 16) & 1u);
    return (unsigned short)(u >> 16);
}

__global__ __launch_bounds__(128, 2)
void attn_v1_kernel(const float* __restrict__ Q, const float* __restrict__ K,
                    const float* __restrict__ V, float* __restrict__ O) {
    __shared__ __align__(16) unsigned short lds_q[64 * 64];
    __shared__ __align__(16) unsigned short lds_k[64 * 64];
    __shared__ __align__(16) unsigned short lds_v[64 * 64];

    const int tid = threadIdx.x, lane = tid & 63, wv = tid >> 6;
    const int lq = lane & 15, g = lane >> 4;
    const int bid = blockIdx.x, xcd = bid & 7, slot = bid >> 3;
    const int qt = slot & 31;
    const int bh = ((slot >> 5) << 3) | xcd;
    const int b = bh >> 3, h = bh & 7;
    const size_t base = ((size_t)b * 2048 * 8 + (size_t)h) * 64;
    const float* Qg = Q + base; const float* Kg = K + base;
    const float* Vg = V + base; float* Og = O + base;
    const int q0 = qt * 64;
    const float S2E = 0.125f * 1.44269504088896341f;

#pragma unroll
    for (int p = 0; p < 16; ++p) {
        int r = (tid >> 5) + p * 4, e = (tid & 31) * 2;
        const float* src = Qg + (size_t)(q0 + r) * 512 + e;
        unsigned pk = (unsigned)f2bf(src[0]) | ((unsigned)f2bf(src[1]) << 16);
        *(unsigned*)&lds_q[(r * 64 + e) ^ ((r & 7) << 3)] = pk;
    }
    __syncthreads();
    short8 qf[2][2];
#pragma unroll
    for (int qc = 0; qc < 2; ++qc) {
        int row = wv * 32 + qc * 16 + lq;
#pragma unroll
        for (int j = 0; j < 2; ++j)
            qf[qc][j] = *(const short8*)&lds_q[(row * 64 + j * 32 + g * 8) ^ ((row & 7) << 3)];
    }
    f32x4 acc[2][4];
#pragma unroll
    for (int qc = 0; qc < 2; ++qc)
#pragma unroll
        for (int dc = 0; dc < 4; ++dc) acc[qc][dc] = (f32x4){0.f, 0.f, 0.f, 0.f};
    float mrow[2] = {-1e30f, -1e30f}, lrow[2] = {0.f, 0.f};

    for (int t = 0; t < 32; ++t) {
        const int kv0 = t * 64;
        __syncthreads();
#pragma unroll
        for (int p = 0; p < 16; ++p) {
            int r = (tid >> 5) + p * 4, e = (tid & 31) * 2;
            const float* src = Kg + (size_t)(kv0 + r) * 512 + e;
            unsigned pk = (unsigned)f2bf(src[0]) | ((unsigned)f2bf(src[1]) << 16);
            *(unsigned*)&lds_k[(r * 64 + e) ^ ((r & 7) << 3)] = pk;
        }
#pragma unroll
        for (int p = 0; p < 16; ++p) {
            int d = tid & 63, kv = (p * 2 + (tid >> 6)) * 2;
            float v0 = Vg[(size_t)(kv0 + kv) * 512 + d];
            float v1 = Vg[(size_t)(kv0 + kv + 1) * 512 + d];
            union { _Float16 hh[2]; unsigned u; } pk;
            pk.hh[0] = (_Float16)v0; pk.hh[1] = (_Float16)v1;
            *(unsigned*)&lds_v[(d * 64 + kv) ^ ((d & 15) << 2)] = pk.u;
        }
        __syncthreads();
        f32x4 sfr[2][4];
#pragma unroll
        for (int kc = 0; kc < 4; ++kc) {
            int row = kc * 16 + lq;
            short8 kf0 = *(const short8*)&lds_k[(row * 64 + 0 + g * 8) ^ ((row & 7) << 3)];
            short8 kf1 = *(const short8*)&lds_k[(row * 64 + 32 + g * 8) ^ ((row & 7) << 3)];
#pragma unroll
            for (int qc = 0; qc < 2; ++qc) {
                f32x4 s = __builtin_amdgcn_mfma_f32_16x16x32_bf16(kf0, qf[qc][0], (f32x4){0.f,0.f,0.f,0.f}, 0, 0, 0);
                s = __builtin_amdgcn_mfma_f32_16x16x32_bf16(kf1, qf[qc][1], s, 0, 0, 0);
                sfr[qc][kc] = s;
            }
        }
        half4 pfv[2][4];
#pragma unroll
        for (int qc = 0; qc < 2; ++qc) {
            float smax = -1e30f;
#pragma unroll
            for (int kc = 0; kc < 4; ++kc)
#pragma unroll
                for (int r = 0; r < 4; ++r) smax = fmaxf(smax, sfr[qc][kc][r]);
            smax = fmaxf(smax, __shfl_xor(smax, 16));
            smax = fmaxf(smax, __shfl_xor(smax, 32));
            float mn = fmaxf(mrow[qc], smax);
            float alpha = __builtin_amdgcn_exp2f((mrow[qc] - mn) * S2E);
            mrow[qc] = mn;
            float msc = mn * S2E, psum = 0.f;
#pragma unroll
            for (int kc = 0; kc < 4; ++kc)
#pragma unroll
                for (int r = 0; r < 4; ++r) {
                    float p = __builtin_amdgcn_exp2f(sfr[qc][kc][r] * S2E - msc);
                    psum += p;
                    pfv[qc][kc][r] = (_Float16)p;
                }
            psum += __shfl_xor(psum, 16);
            psum += __shfl_xor(psum, 32);
            lrow[qc] = lrow[qc] * alpha + psum;
#pragma unroll
            for (int dc = 0; dc < 4; ++dc) acc[qc][dc] *= alpha;
        }
#pragma unroll
        for (int dc = 0; dc < 4; ++dc) {
            int dd = dc * 16 + lq;
#pragma unroll
            for (int kc = 0; kc < 4; ++kc) {
                half4 vf = *(const half4*)&lds_v[(dd * 64 + kc * 16 + g * 4) ^ ((dd & 15) << 2)];
                acc[0][dc] = __builtin_amdgcn_mfma_f32_16x16x16f16(vf, pfv[0][kc], acc[0][dc], 0, 0, 0);
                acc[1][dc] = __builtin_amdgcn_mfma_f32_16x16x16f16(vf, pfv[1][kc], acc[1][dc], 0, 0, 0);
            }
        }
    }
#pragma unroll
    for (int qc = 0; qc < 2; ++qc) {
        float inv = 1.f / lrow[qc];
        int qrow = q0 + wv * 32 + qc * 16 + lq;
#pragma unroll
        for (int dc = 0; dc < 4; ++dc) {
            f32x4 o = acc[qc][dc] * inv;
            *(f32x4*)(Og + (size_t)qrow * 512 + dc * 16 + g * 4) = o;
        }
    }
}

extern "C" void kernel_launch(void* const* d_in, const int* in_sizes, int n_in,
                              void* d_out, int out_size, void* d_ws, size_t ws_size,
                              hipStream_t stream) {
    const float* Q = (const float*)d_in[0];
    const float* K = (const float*)d_in[1];
    const float* V = (const float*)d_in[2];
    float* O = (float*)d_out;

    const size_t per = (size_t)32 * 2048 * 64;            // elements per tensor
    const size_t need = 2 * per * sizeof(unsigned short); // 16 MB (K + V only)
    if (ws_size >= need) {
        unsigned short* wsK = (unsigned short*)d_ws;
        unsigned short* wsV = wsK + per;
        cvt_kv_kernel<<<dim3(8192), dim3(256), 0, stream>>>(K, V, wsK, wsV);
        attn_v4_kernel<<<dim3(512), dim3(512), 0, stream>>>(Q, wsK, wsV, O);
    } else {
        attn_v1_kernel<<<dim3(1024), dim3(128), 0, stream>>>(Q, K, V, O);
    }
}

// Round 7
// 58.508 us; speedup vs baseline: 1.7260x; 1.0085x over previous
//
#include <hip/hip_runtime.h>

typedef __attribute__((ext_vector_type(4)))  float    f32x4;
typedef __attribute__((ext_vector_type(16))) float    f32x16;
typedef __attribute__((ext_vector_type(8)))  _Float16 half8;
typedef __attribute__((ext_vector_type(2)))  __fp16   fp16x2;
typedef __attribute__((ext_vector_type(4)))  _Float16 half4;
typedef __attribute__((ext_vector_type(8)))  short    short8;

#define SCL2E 0.18033688011112042f   // (1/8) * log2(e)  — folded into Q

__device__ __forceinline__ unsigned short f2h_bits(float x) {
    union { _Float16 h; unsigned short u; } c;
    c.h = (_Float16)x;
    return c.u;
}

__device__ __forceinline__ void gl_lds16(const unsigned short* g, unsigned short* l) {
    __builtin_amdgcn_global_load_lds((const __attribute__((address_space(1))) void*)g,
                                     (__attribute__((address_space(3))) void*)l, 16, 0, 0);
}

// ============ prepass (fused): K and V^T -> f16 in [bh][tile][32][128] granule-swizzled ============
// Per 64x64 f16 tile: LDS-row R (0..31) holds rows {R, R+32} side by side (half = 0/1).
// MFMA fragment permutation: e' = swap bits 2,3 of e. granule = (half*8 + (e'>>3)) ^ (R&15);
// short index = granule*8 + (e'&7).
__global__ __launch_bounds__(256)
void cvt_kv_kernel(const float* __restrict__ K, const float* __restrict__ V,
                   unsigned short* __restrict__ wsK, unsigned short* __restrict__ wsV) {
    int bid = blockIdx.x;                           // 0..8191
    if (bid < 4096) {
        // K: [b][kv][h][e] -> wsK tile row R=kv&31, half=(kv>>5)&1
        int t   = bid * 256 + threadIdx.x;
        int eg  = t & 15;                           // e = eg*4
        int gr  = t >> 4;
        int kv  = gr & 2047, bh = gr >> 11;
        int b = bh >> 3, h = bh & 7;
        const float* sp = K + (((size_t)b * 2048 + kv) * 8 + h) * 64 + eg * 4;
        f32x4 v = *(const f32x4*)sp;
        int T = kv >> 6, R = kv & 31, half = (kv >> 5) & 1;
        int egp = (eg & ~3) | ((eg & 1) << 1) | ((eg >> 1) & 1);   // swap e bits 2,3
        int gnl = (half * 8 + (egp >> 1)) ^ (R & 15);
        size_t idx = (((size_t)bh * 32 + T) * 32 + R) * 128 + gnl * 8 + (egp & 1) * 4;
        union { unsigned short s[4]; unsigned long long u; } o;
        o.s[0] = f2h_bits(v[0]); o.s[1] = f2h_bits(v[1]);
        o.s[2] = f2h_bits(v[2]); o.s[3] = f2h_bits(v[3]);
        *(unsigned long long*)(wsK + idx) = o.u;
    } else {
        // V -> V^T tile: row R=d&31, half=d>>5, inner = kv_local (bit2<->3 swapped)
        int t   = (bid - 4096) * 256 + threadIdx.x;
        int d   = t & 63;
        int g   = t >> 6;
        int kv4 = g & 511, bh = g >> 9;
        int b = bh >> 3, h = bh & 7;
        int kv = kv4 * 4;
        const float* sp = V + (((size_t)b * 2048 + kv) * 8 + h) * 64 + d;
        float v0 = sp[0], v1 = sp[512], v2 = sp[1024], v3 = sp[1536];
        int T = kv >> 6, R = d & 31, halfd = d >> 5;
        int kvg  = (kv >> 2) & 15;                                   // 4-group within 64-kv tile
        int kvgp = (kvg & ~3) | ((kvg & 1) << 1) | ((kvg >> 1) & 1); // swap kv bits 2,3
        int gnl  = (halfd * 8 + (kvgp >> 1)) ^ (R & 15);
        size_t idx = (((size_t)bh * 32 + T) * 32 + R) * 128 + gnl * 8 + (kvgp & 1) * 4;
        union { unsigned short s[4]; unsigned long long u; } o;
        o.s[0] = f2h_bits(v0); o.s[1] = f2h_bits(v1);
        o.s[2] = f2h_bits(v2); o.s[3] = f2h_bits(v3);
        *(unsigned long long*)(wsV + idx) = o.u;
    }
}

// ---------------- main: 8 waves = 4 q-chunks x 2 kv-halves, no-max softmax ----------------
__global__ __launch_bounds__(512, 4)
void attn_v6_kernel(const float* __restrict__ Q,
                    const unsigned short* __restrict__ wsK,
                    const unsigned short* __restrict__ wsV,
                    float* __restrict__ O) {
    __shared__ __align__(16) unsigned short lds[2][2][2][4096];   // 64 KB  [buf][K/V][kh][32*128]
    __shared__ __align__(16) unsigned short lds_q[128 * 64];      // 16 KB

    const int tid  = threadIdx.x;
    const int lane = tid & 63;
    const int w    = tid >> 6;          // wave 0..7
    const int qw   = w & 3;             // q chunk
    const int kh   = w >> 2;            // kv half
    const int lq   = lane & 31;
    const int hi   = lane >> 5;

    const int bid = blockIdx.x;
    const int xcd = bid & 7, slot = bid >> 3;
    const int qt  = slot & 15;
    const int bh  = ((slot >> 4) << 3) | xcd;   // XCD-local bh
    const int q0  = qt * 128;
    const int b   = bh >> 3, h = bh & 7;

    const unsigned short* Ksrc = wsK + (size_t)bh * 32 * 4096;   // [tile][32][128]
    const unsigned short* Vsrc = wsV + (size_t)bh * 32 * 4096;
    float* Og = O + ((size_t)b * 2048 * 8 + (size_t)h) * 64;

    // ---- stage Q (scale folded) into lds_q, perm+swizzled; coalesced f32x4 loads ----
#pragma unroll
    for (int p = 0; p < 4; ++p) {
        int t  = tid + 512 * p;          // 0..2047
        int eg = t & 15;
        int r  = t >> 4;                 // 0..127
        const float* sp = Q + (((size_t)b * 2048 + q0 + r) * 8 + h) * 64 + eg * 4;
        f32x4 v = *(const f32x4*)sp;
        int cg = (eg & ~3) | ((eg & 1) << 1) | ((eg >> 1) & 1);
        cg ^= (r & 7) << 1;
        union { unsigned short s[4]; unsigned long long u; } o;
        o.s[0] = f2h_bits(v[0] * SCL2E); o.s[1] = f2h_bits(v[1] * SCL2E);
        o.s[2] = f2h_bits(v[2] * SCL2E); o.s[3] = f2h_bits(v[3] * SCL2E);
        *(unsigned long long*)&lds_q[r * 64 + cg * 4] = o.u;
    }

    // stage tile 0 (both kv halves): tiles T = kh*16 + t
    {
        gl_lds16(Ksrc + (size_t)0  * 4096 + tid * 8, &lds[0][0][0][tid * 8]);
        gl_lds16(Vsrc + (size_t)0  * 4096 + tid * 8, &lds[0][1][0][tid * 8]);
        gl_lds16(Ksrc + (size_t)16 * 4096 + tid * 8, &lds[0][0][1][tid * 8]);
        gl_lds16(Vsrc + (size_t)16 * 4096 + tid * 8, &lds[0][1][1][tid * 8]);
    }
    __syncthreads();

    // K/V fragment granule offsets (conflict-free: 16 slots per 256B row)
    int of0[4], of1[4];
#pragma unroll
    for (int ks = 0; ks < 4; ++ks) {
        of0[ks] = (((ks * 2 + hi)     ^ (lq & 15)) << 3);   // half 0: rows 0..31
        of1[ks] = (((8 + ks * 2 + hi) ^ (lq & 15)) << 3);   // half 1: rows 32..63
    }

    half8 qf[4];
    {
        int qrow = qw * 32 + lq;
#pragma unroll
        for (int ks = 0; ks < 4; ++ks) {
            int offQ = (ks * 16 + hi * 8) ^ ((lq & 7) << 3);
            qf[ks] = *(const half8*)&lds_q[qrow * 64 + offQ];
        }
    }

    f32x16 acc0 = {0.f,0.f,0.f,0.f,0.f,0.f,0.f,0.f,0.f,0.f,0.f,0.f,0.f,0.f,0.f,0.f};
    f32x16 acc1 = acc0;
    float lrowA = 0.f, lrowB = 0.f;
    const fp16x2 vone = {(__fp16)1.0f, (__fp16)1.0f};

    for (int t = 0; t < 16; ++t) {
        const int cur = t & 1;
        if (t + 1 < 16) {
            const int nxt = cur ^ 1;
            gl_lds16(Ksrc + (size_t)(t + 1)  * 4096 + tid * 8, &lds[nxt][0][0][tid * 8]);
            gl_lds16(Vsrc + (size_t)(t + 1)  * 4096 + tid * 8, &lds[nxt][1][0][tid * 8]);
            gl_lds16(Ksrc + (size_t)(t + 17) * 4096 + tid * 8, &lds[nxt][0][1][tid * 8]);
            gl_lds16(Vsrc + (size_t)(t + 17) * 4096 + tid * 8, &lds[nxt][1][1][tid * 8]);
        }

        // ---- S^T = K · Q^T : D col=q=lq, row=kv_local=(r&3)+8(r>>2)+4hi ----
        const unsigned short* kb = &lds[cur][0][kh][0];
        f32x16 s0 = {0.f,0.f,0.f,0.f,0.f,0.f,0.f,0.f,0.f,0.f,0.f,0.f,0.f,0.f,0.f,0.f};
        f32x16 s1 = s0;
        __builtin_amdgcn_s_setprio(1);
#pragma unroll
        for (int ks = 0; ks < 4; ++ks) {
            half8 kf0 = *(const half8*)&kb[lq * 128 + of0[ks]];
            half8 kf1 = *(const half8*)&kb[lq * 128 + of1[ks]];
            s0 = __builtin_amdgcn_mfma_f32_32x32x16_f16(kf0, qf[ks], s0, 0, 0, 0);
            s1 = __builtin_amdgcn_mfma_f32_32x32x16_f16(kf1, qf[ks], s1, 0, 0, 0);
        }
        __builtin_amdgcn_s_setprio(0);

        // ---- p = exp2(s) directly; pack to f16; psum via fdot2 ----
        half8 pf[4];
        float pA = 0.f, pB = 0.f;
#pragma unroll
        for (int hm = 0; hm < 2; ++hm) {
            const f32x16& sb = hm ? s1 : s0;
#pragma unroll
            for (int hk = 0; hk < 2; ++hk) {
                union { fp16x2 h2[4]; half8 v; } u;
#pragma unroll
                for (int j = 0; j < 4; ++j) {
                    float e0 = __builtin_amdgcn_exp2f(sb[8 * hk + 2 * j]);
                    float e1 = __builtin_amdgcn_exp2f(sb[8 * hk + 2 * j + 1]);
                    u.h2[j] = __builtin_amdgcn_cvt_pkrtz(e0, e1);
#if __has_builtin(__builtin_amdgcn_fdot2)
                    if (hm == 0) pA = __builtin_amdgcn_fdot2(u.h2[j], vone, pA, false);
                    else         pB = __builtin_amdgcn_fdot2(u.h2[j], vone, pB, false);
#else
                    if (hm == 0) pA += e0 + e1; else pB += e0 + e1;
#endif
                }
                pf[2 * hm + hk] = u.v;
            }
        }
        lrowA += pA; lrowB += pB;

        // ---- O^T += V^T · P^T ----
        const unsigned short* vb = &lds[cur][1][kh][0];
        __builtin_amdgcn_s_setprio(1);
#pragma unroll
        for (int kc = 0; kc < 4; ++kc) {
            half8 vf0 = *(const half8*)&vb[lq * 128 + of0[kc]];
            half8 vf1 = *(const half8*)&vb[lq * 128 + of1[kc]];
            acc0 = __builtin_amdgcn_mfma_f32_32x32x16_f16(vf0, pf[kc], acc0, 0, 0, 0);
            acc1 = __builtin_amdgcn_mfma_f32_32x32x16_f16(vf1, pf[kc], acc1, 0, 0, 0);
        }
        __builtin_amdgcn_s_setprio(0);

        __syncthreads();
    }

    // ---- epilogue: merge lane halves of l, then merge kv halves via LDS (plain add) ----
    float lrow = lrowA + lrowB;
    lrow += __shfl_xor(lrow, 32);

    float* mlds = (float*)&lds[0][0][0][0];   // 4*64*36*4 = 36,864 B
    const int mslot = (qw * 64 + lane) * 36;
    if (kh) {
        float* dst = mlds + mslot;
#pragma unroll
        for (int a = 0; a < 4; ++a) {
            *(f32x4*)(dst + 4 * a)      = (f32x4){acc0[4*a], acc0[4*a+1], acc0[4*a+2], acc0[4*a+3]};
            *(f32x4*)(dst + 16 + 4 * a) = (f32x4){acc1[4*a], acc1[4*a+1], acc1[4*a+2], acc1[4*a+3]};
        }
        dst[32] = lrow;
    }
    __syncthreads();
    if (!kh) {
        const float* src = mlds + mslot;
        float inv = 1.0f / (lrow + src[32]);

        const int qg = q0 + qw * 32 + lq;
        float* orow = Og + (size_t)qg * 512;
#pragma unroll
        for (int a = 0; a < 4; ++a) {
            f32x4 p0 = *(const f32x4*)(src + 4 * a);
            f32x4 p1 = *(const f32x4*)(src + 16 + 4 * a);
            f32x4 o0, o1;
#pragma unroll
            for (int i = 0; i < 4; ++i) {
                o0[i] = (acc0[4 * a + i] + p0[i]) * inv;
                o1[i] = (acc1[4 * a + i] + p1[i]) * inv;
            }
            *(f32x4*)(orow + 8 * a + 4 * hi)      = o0;
            *(f32x4*)(orow + 32 + 8 * a + 4 * hi) = o1;
        }
    }
}

// ================= fallback (round-1 kernel, passes) =================
__device__ __forceinline__ unsigned short f2bf(float f) {
    union { float f; unsigned u; } v; v.f = f;
    unsigned u = v.u;
    u += 0x7fffu + ((u >> 16) & 1u);
    return (unsigned short)(u >> 16);
}

__global__ __launch_bounds__(128, 2)
void attn_v1_kernel(const float* __restrict__ Q, const float* __restrict__ K,
                    const float* __restrict__ V, float* __restrict__ O) {
    __shared__ __align__(16) unsigned short lds_q[64 * 64];
    __shared__ __align__(16) unsigned short lds_k[64 * 64];
    __shared__ __align__(16) unsigned short lds_v[64 * 64];

    const int tid = threadIdx.x, lane = tid & 63, wv = tid >> 6;
    const int lq = lane & 15, g = lane >> 4;
    const int bid = blockIdx.x, xcd = bid & 7, slot = bid >> 3;
    const int qt = slot & 31;
    const int bh = ((slot >> 5) << 3) | xcd;
    const int b = bh >> 3, h = bh & 7;
    const size_t base = ((size_t)b * 2048 * 8 + (size_t)h) * 64;
    const float* Qg = Q + base; const float* Kg = K + base;
    const float* Vg = V + base; float* Og = O + base;
    const int q0 = qt * 64;
    const float S2E = 0.125f * 1.44269504088896341f;

#pragma unroll
    for (int p = 0; p < 16; ++p) {
        int r = (tid >> 5) + p * 4, e = (tid & 31) * 2;
        const float* src = Qg + (size_t)(q0 + r) * 512 + e;
        unsigned pk = (unsigned)f2bf(src[0]) | ((unsigned)f2bf(src[1]) << 16);
        *(unsigned*)&lds_q[(r * 64 + e) ^ ((r & 7) << 3)] = pk;
    }
    __syncthreads();
    short8 qf[2][2];
#pragma unroll
    for (int qc = 0; qc < 2; ++qc) {
        int row = wv * 32 + qc * 16 + lq;
#pragma unroll
        for (int j = 0; j < 2; ++j)
            qf[qc][j] = *(const short8*)&lds_q[(row * 64 + j * 32 + g * 8) ^ ((row & 7) << 3)];
    }
    f32x4 acc[2][4];
#pragma unroll
    for (int qc = 0; qc < 2; ++qc)
#pragma unroll
        for (int dc = 0; dc < 4; ++dc) acc[qc][dc] = (f32x4){0.f, 0.f, 0.f, 0.f};
    float mrow[2] = {-1e30f, -1e30f}, lrow[2] = {0.f, 0.f};

    for (int t = 0; t < 32; ++t) {
        const int kv0 = t * 64;
        __syncthreads();
#pragma unroll
        for (int p = 0; p < 16; ++p) {
            int r = (tid >> 5) + p * 4, e = (tid & 31) * 2;
            const float* src = Kg + (size_t)(kv0 + r) * 512 + e;
            unsigned pk = (unsigned)f2bf(src[0]) | ((unsigned)f2bf(src[1]) << 16);
            *(unsigned*)&lds_k[(r * 64 + e) ^ ((r & 7) << 3)] = pk;
        }
#pragma unroll
        for (int p = 0; p < 16; ++p) {
            int d = tid & 63, kv = (p * 2 + (tid >> 6)) * 2;
            float v0 = Vg[(size_t)(kv0 + kv) * 512 + d];
            float v1 = Vg[(size_t)(kv0 + kv + 1) * 512 + d];
            union { _Float16 hh[2]; unsigned u; } pk;
            pk.hh[0] = (_Float16)v0; pk.hh[1] = (_Float16)v1;
            *(unsigned*)&lds_v[(d * 64 + kv) ^ ((d & 15) << 2)] = pk.u;
        }
        __syncthreads();
        f32x4 sfr[2][4];
#pragma unroll
        for (int kc = 0; kc < 4; ++kc) {
            int row = kc * 16 + lq;
            short8 kf0 = *(const short8*)&lds_k[(row * 64 + 0 + g * 8) ^ ((row & 7) << 3)];
            short8 kf1 = *(const short8*)&lds_k[(row * 64 + 32 + g * 8) ^ ((row & 7) << 3)];
#pragma unroll
            for (int qc = 0; qc < 2; ++qc) {
                f32x4 s = __builtin_amdgcn_mfma_f32_16x16x32_bf16(kf0, qf[qc][0], (f32x4){0.f,0.f,0.f,0.f}, 0, 0, 0);
                s = __builtin_amdgcn_mfma_f32_16x16x32_bf16(kf1, qf[qc][1], s, 0, 0, 0);
                sfr[qc][kc] = s;
            }
        }
        half4 pfv[2][4];
#pragma unroll
        for (int qc = 0; qc < 2; ++qc) {
            float smax = -1e30f;
#pragma unroll
            for (int kc = 0; kc < 4; ++kc)
#pragma unroll
                for (int r = 0; r < 4; ++r) smax = fmaxf(smax, sfr[qc][kc][r]);
            smax = fmaxf(smax, __shfl_xor(smax, 16));
            smax = fmaxf(smax, __shfl_xor(smax, 32));
            float mn = fmaxf(mrow[qc], smax);
            float alpha = __builtin_amdgcn_exp2f((mrow[qc] - mn) * S2E);
            mrow[qc] = mn;
            float msc = mn * S2E, psum = 0.f;
#pragma unroll
            for (int kc = 0; kc < 4; ++kc)
#pragma unroll
                for (int r = 0; r < 4; ++r) {
                    float p = __builtin_amdgcn_exp2f(sfr[qc][kc][r] * S2E - msc);
                    psum += p;
                    pfv[qc][kc][r] = (_Float16)p;
                }
            psum += __shfl_xor(psum, 16);
            psum += __shfl_xor(psum, 32);
            lrow[qc] = lrow[qc] * alpha + psum;
#pragma unroll
            for (int dc = 0; dc < 4; ++dc) acc[qc][dc] *= alpha;
        }
#pragma unroll
        for (int dc = 0; dc < 4; ++dc) {
            int dd = dc * 16 + lq;
#pragma unroll
            for (int kc = 0; kc < 4; ++kc) {
                half4 vf = *(const half4*)&lds_v[(dd * 64 + kc * 16 + g * 4) ^ ((dd & 15) << 2)];
                acc[0][dc] = __builtin_amdgcn_mfma_f32_16x16x16f16(vf, pfv[0][kc], acc[0][dc], 0, 0, 0);
                acc[1][dc] = __builtin_amdgcn_mfma_f32_16x16x16f16(vf, pfv[1][kc], acc[1][dc], 0, 0, 0);
            }
        }
    }
#pragma unroll
    for (int qc = 0; qc < 2; ++qc) {
        float inv = 1.f / lrow[qc];
        int qrow = q0 + wv * 32 + qc * 16 + lq;
#pragma unroll
        for (int dc = 0; dc < 4; ++dc) {
            f32x4 o = acc[qc][dc] * inv;
            *(f32x4*)(Og + (size_t)qrow * 512 + dc * 16 + g * 4) = o;
        }
    }
}

extern "C" void kernel_launch(void* const* d_in, const int* in_sizes, int n_in,
                              void* d_out, int out_size, void* d_ws, size_t ws_size,
                              hipStream_t stream) {
    const float* Q = (const float*)d_in[0];
    const float* K = (const float*)d_in[1];
    const float* V = (const float*)d_in[2];
    float* O = (float*)d_out;

    const size_t per = (size_t)32 * 2048 * 64;            // elements per tensor
    const size_t need = 2 * per * sizeof(unsigned short); // 16 MB (K + V only)
    if (ws_size >= need) {
        unsigned short* wsK = (unsigned short*)d_ws;
        unsigned short* wsV = wsK + per;
        cvt_kv_kernel<<<dim3(8192), dim3(256), 0, stream>>>(K, V, wsK, wsV);
        attn_v6_kernel<<<dim3(512), dim3(512), 0, stream>>>(Q, wsK, wsV, O);
    } else {
        attn_v1_kernel<<<dim3(1024), dim3(128), 0, stream>>>(Q, K, V, O);
    }
}